// Round 2
// baseline (7240.847 us; speedup 1.0000x reference)
//
#include <hip/hip_runtime.h>

#define DEV_INLINE __device__ __forceinline__

constexpr int NF = 26;   // input features
constexpr int H1 = 24;   // layer-1 hidden
constexpr int H2 = 8;    // layer-2 hidden
constexpr int T  = 5;    // sequence length

DEV_INLINE float fast_rcp(float x) { return __builtin_amdgcn_rcpf(x); }
// sigmoid(x) = 1/(1+exp(-x))
DEV_INLINE float fast_sigmoid(float x) { return fast_rcp(1.0f + __expf(-x)); }
// tanh(x) = 2/(1+exp(-2x)) - 1
DEV_INLINE float fast_tanh(float x) {
    return fmaf(2.0f, fast_rcp(1.0f + __expf(-2.0f * x)), -1.0f);
}

// LDS weight layout: gate-interleaved so one ds_read_b128 (broadcast) feeds
// 4 independent FMA chains (i,f,g,o).
//   s_wih1[j][i][g], s_whh1[j][k][g], s_wih2[j][k][g], s_whh2[j][k][g]
//   s_b1[j][g] = b_ih1+b_hh1 pre-added; s_b2 likewise.
// Total: (2496+2304+768+256+96+32)*4B = 23808 B per block.

__global__ __launch_bounds__(256) void lstm2_fused(
    const float* __restrict__ x,
    const float* __restrict__ w_ih1, const float* __restrict__ w_hh1,
    const float* __restrict__ b_ih1, const float* __restrict__ b_hh1,
    const float* __restrict__ w_ih2, const float* __restrict__ w_hh2,
    const float* __restrict__ b_ih2, const float* __restrict__ b_hh2,
    float* __restrict__ out, int batch)
{
    __shared__ float s_wih1[H1 * NF * 4];
    __shared__ float s_whh1[H1 * H1 * 4];
    __shared__ float s_wih2[H2 * H1 * 4];
    __shared__ float s_whh2[H2 * H2 * 4];
    __shared__ float s_b1[H1 * 4];
    __shared__ float s_b2[H2 * 4];

    const int tid = threadIdx.x;

    // ---- cooperative repack: global (gate-major rows) -> LDS (gate-interleaved) ----
    for (int e = tid; e < H1 * NF * 4; e += 256) {
        int g = e & 3, r = e >> 2, i = r % NF, j = r / NF;
        s_wih1[e] = w_ih1[(g * H1 + j) * NF + i];
    }
    for (int e = tid; e < H1 * H1 * 4; e += 256) {
        int g = e & 3, r = e >> 2, k = r % H1, j = r / H1;
        s_whh1[e] = w_hh1[(g * H1 + j) * H1 + k];
    }
    for (int e = tid; e < H2 * H1 * 4; e += 256) {
        int g = e & 3, r = e >> 2, k = r % H1, j = r / H1;
        s_wih2[e] = w_ih2[(g * H2 + j) * H1 + k];
    }
    for (int e = tid; e < H2 * H2 * 4; e += 256) {
        int g = e & 3, r = e >> 2, k = r % H2, j = r / H2;
        s_whh2[e] = w_hh2[(g * H2 + j) * H2 + k];
    }
    if (tid < H1 * 4) {
        int g = tid & 3, j = tid >> 2;
        s_b1[tid] = b_ih1[g * H1 + j] + b_hh1[g * H1 + j];
    }
    if (tid < H2 * 4) {
        int g = tid & 3, j = tid >> 2;
        s_b2[tid] = b_ih2[g * H2 + j] + b_hh2[g * H2 + j];
    }
    __syncthreads();

    const float4* __restrict__ wih1v = reinterpret_cast<const float4*>(s_wih1);
    const float4* __restrict__ whh1v = reinterpret_cast<const float4*>(s_whh1);
    const float4* __restrict__ wih2v = reinterpret_cast<const float4*>(s_wih2);
    const float4* __restrict__ whh2v = reinterpret_cast<const float4*>(s_whh2);
    const float4* __restrict__ b1v   = reinterpret_cast<const float4*>(s_b1);
    const float4* __restrict__ b2v   = reinterpret_cast<const float4*>(s_b2);

    const int b = blockIdx.x * blockDim.x + tid;
    if (b >= batch) return;
    const float* __restrict__ xb = x + (size_t)b * (T * NF);

    float h1[H1], c1[H1];
    float h2v[H2], c2[H2];
    #pragma unroll
    for (int j = 0; j < H1; ++j) { h1[j] = 0.0f; c1[j] = 0.0f; }
    #pragma unroll
    for (int j = 0; j < H2; ++j) { h2v[j] = 0.0f; c2[j] = 0.0f; }

    for (int t = 0; t < T; ++t) {
        // ---- load x_t (26 floats, 8B-aligned) ----
        float xt[NF];
        const float2* xp = reinterpret_cast<const float2*>(xb + t * NF);
        #pragma unroll
        for (int i = 0; i < NF / 2; ++i) {
            float2 v = xp[i];
            xt[2 * i] = v.x;
            xt[2 * i + 1] = v.y;
        }

        // ---- layer 1 ----
        float h1n[H1];
        #pragma unroll
        for (int j = 0; j < H1; ++j) {
            float4 bv = b1v[j];
            float ai = bv.x, af = bv.y, ag = bv.z, ao = bv.w;
            #pragma unroll
            for (int i = 0; i < NF; ++i) {
                const float xi = xt[i];
                float4 w = wih1v[j * NF + i];     // ds_read_b128 broadcast
                ai = fmaf(w.x, xi, ai);
                af = fmaf(w.y, xi, af);
                ag = fmaf(w.z, xi, ag);
                ao = fmaf(w.w, xi, ao);
            }
            if (t > 0) {  // h1 == 0 at t==0: recurrent part contributes exactly 0
                #pragma unroll
                for (int k = 0; k < H1; ++k) {
                    const float hk = h1[k];
                    float4 w = whh1v[j * H1 + k];
                    ai = fmaf(w.x, hk, ai);
                    af = fmaf(w.y, hk, af);
                    ag = fmaf(w.z, hk, ag);
                    ao = fmaf(w.w, hk, ao);
                }
            }
            const float ig = fast_sigmoid(ai);
            const float fg = fast_sigmoid(af);
            const float gg = fast_tanh(ag);
            const float og = fast_sigmoid(ao);
            const float c  = fmaf(fg, c1[j], ig * gg);  // c1==0 at t==0: exact
            c1[j]  = c;
            h1n[j] = og * fast_tanh(c);
        }
        #pragma unroll
        for (int j = 0; j < H1; ++j) h1[j] = h1n[j];

        // ---- layer 2 (consumes h1 of this timestep) ----
        float h2n[H2];
        #pragma unroll
        for (int j = 0; j < H2; ++j) {
            float4 bv = b2v[j];
            float ai = bv.x, af = bv.y, ag = bv.z, ao = bv.w;
            #pragma unroll
            for (int k = 0; k < H1; ++k) {
                const float hk = h1[k];
                float4 w = wih2v[j * H1 + k];
                ai = fmaf(w.x, hk, ai);
                af = fmaf(w.y, hk, af);
                ag = fmaf(w.z, hk, ag);
                ao = fmaf(w.w, hk, ao);
            }
            if (t > 0) {
                #pragma unroll
                for (int k = 0; k < H2; ++k) {
                    const float hk = h2v[k];
                    float4 w = whh2v[j * H2 + k];
                    ai = fmaf(w.x, hk, ai);
                    af = fmaf(w.y, hk, af);
                    ag = fmaf(w.z, hk, ag);
                    ao = fmaf(w.w, hk, ao);
                }
            }
            const float ig = fast_sigmoid(ai);
            const float fg = fast_sigmoid(af);
            const float gg = fast_tanh(ag);
            const float og = fast_sigmoid(ao);
            const float c  = fmaf(fg, c2[j], ig * gg);
            c2[j]  = c;
            h2n[j] = og * fast_tanh(c);
        }
        #pragma unroll
        for (int j = 0; j < H2; ++j) h2v[j] = h2n[j];
    }

    // ---- write final h2: 32 contiguous bytes per thread, coalesced ----
    float4* op = reinterpret_cast<float4*>(out + (size_t)b * H2);
    op[0] = make_float4(h2v[0], h2v[1], h2v[2], h2v[3]);
    op[1] = make_float4(h2v[4], h2v[5], h2v[6], h2v[7]);
}

extern "C" void kernel_launch(void* const* d_in, const int* in_sizes, int n_in,
                              void* d_out, int out_size, void* d_ws, size_t ws_size,
                              hipStream_t stream)
{
    const float* x     = (const float*)d_in[0];
    const float* w_ih1 = (const float*)d_in[1];
    const float* w_hh1 = (const float*)d_in[2];
    const float* b_ih1 = (const float*)d_in[3];
    const float* b_hh1 = (const float*)d_in[4];
    const float* w_ih2 = (const float*)d_in[5];
    const float* w_hh2 = (const float*)d_in[6];
    const float* b_ih2 = (const float*)d_in[7];
    const float* b_hh2 = (const float*)d_in[8];
    float* out = (float*)d_out;

    const int batch = in_sizes[0] / (T * NF);
    const int block = 256;
    const int grid  = (batch + block - 1) / block;
    lstm2_fused<<<grid, block, 0, stream>>>(x, w_ih1, w_hh1, b_ih1, b_hh1,
                                            w_ih2, w_hh2, b_ih2, b_hh2,
                                            out, batch);
}

// Round 3
// 342.139 us; speedup vs baseline: 21.1635x; 21.1635x over previous
//
#include <hip/hip_runtime.h>

#define DEV_INLINE __device__ __forceinline__

constexpr int NF = 26;   // input features
constexpr int H1 = 24;   // layer-1 hidden
constexpr int H2 = 8;    // layer-2 hidden
constexpr int T  = 5;    // sequence length

DEV_INLINE float fast_rcp(float x) { return __builtin_amdgcn_rcpf(x); }
// sigmoid(x) = 1/(1+exp(-x))
DEV_INLINE float fast_sigmoid(float x) { return fast_rcp(1.0f + __expf(-x)); }
// tanh(x) = 2/(1+exp(-2x)) - 1
DEV_INLINE float fast_tanh(float x) {
    return fmaf(2.0f, fast_rcp(1.0f + __expf(-2.0f * x)), -1.0f);
}

// LDS weight layout: gate-interleaved float4 so one ds_read_b128 (uniform
// address -> broadcast, conflict-free) feeds 4 independent FMA chains
// (i,f,g,o). Biases pre-added (b_ih+b_hh) at staging.
// Total LDS: (624+576+192+64+24+8)*16B = 23808 B per block.

__global__ __launch_bounds__(256) void lstm2_fused(
    const float* __restrict__ x,
    const float* __restrict__ w_ih1, const float* __restrict__ w_hh1,
    const float* __restrict__ b_ih1, const float* __restrict__ b_hh1,
    const float* __restrict__ w_ih2, const float* __restrict__ w_hh2,
    const float* __restrict__ b_ih2, const float* __restrict__ b_hh2,
    float* __restrict__ out, int batch)
{
    __shared__ float4 s_wih1[H1 * NF];
    __shared__ float4 s_whh1[H1 * H1];
    __shared__ float4 s_wih2[H2 * H1];
    __shared__ float4 s_whh2[H2 * H2];
    __shared__ float4 s_b1[H1];
    __shared__ float4 s_b2[H2];

    const int tid = threadIdx.x;

    // ---- cooperative repack: global (gate-major rows) -> LDS (gate-interleaved) ----
    {
        float* d = reinterpret_cast<float*>(s_wih1);
        for (int e = tid; e < H1 * NF * 4; e += 256) {
            int g = e & 3, r = e >> 2, i = r % NF, j = r / NF;
            d[e] = w_ih1[(g * H1 + j) * NF + i];
        }
        d = reinterpret_cast<float*>(s_whh1);
        for (int e = tid; e < H1 * H1 * 4; e += 256) {
            int g = e & 3, r = e >> 2, k = r % H1, j = r / H1;
            d[e] = w_hh1[(g * H1 + j) * H1 + k];
        }
        d = reinterpret_cast<float*>(s_wih2);
        for (int e = tid; e < H2 * H1 * 4; e += 256) {
            int g = e & 3, r = e >> 2, k = r % H1, j = r / H1;
            d[e] = w_ih2[(g * H2 + j) * H1 + k];
        }
        d = reinterpret_cast<float*>(s_whh2);
        for (int e = tid; e < H2 * H2 * 4; e += 256) {
            int g = e & 3, r = e >> 2, k = r % H2, j = r / H2;
            d[e] = w_hh2[(g * H2 + j) * H2 + k];
        }
        d = reinterpret_cast<float*>(s_b1);
        if (tid < H1 * 4) {
            int g = tid & 3, j = tid >> 2;
            d[tid] = b_ih1[g * H1 + j] + b_hh1[g * H1 + j];
        }
        d = reinterpret_cast<float*>(s_b2);
        if (tid < H2 * 4) {
            int g = tid & 3, j = tid >> 2;
            d[tid] = b_ih2[g * H2 + j] + b_hh2[g * H2 + j];
        }
    }
    __syncthreads();

    const int b = blockIdx.x * blockDim.x + tid;
    if (b >= batch) return;
    const float* __restrict__ xb = x + (size_t)b * (T * NF);

    float h1[H1], c1[H1];
    float h2v[H2], c2[H2];
    #pragma unroll
    for (int j = 0; j < H1; ++j) { h1[j] = 0.0f; c1[j] = 0.0f; }
    #pragma unroll
    for (int j = 0; j < H2; ++j) { h2v[j] = 0.0f; c2[j] = 0.0f; }

    #pragma unroll 1   // keep scheduling regions small: 5x fewer live loads
    for (int t = 0; t < T; ++t) {
        // ---- load x_t (26 floats, 8B-aligned) ----
        float xt[NF];
        const float2* xp = reinterpret_cast<const float2*>(xb + t * NF);
        #pragma unroll
        for (int i = 0; i < NF / 2; ++i) {
            float2 v = xp[i];
            xt[2 * i] = v.x;
            xt[2 * i + 1] = v.y;
        }

        // ---- layer 1 ----
        float h1n[H1];
        #pragma unroll
        for (int j = 0; j < H1; ++j) {
            float4 bv = s_b1[j];
            float ai = bv.x, af = bv.y, ag = bv.z, ao = bv.w;
            #pragma unroll
            for (int i = 0; i < NF; ++i) {
                const float xi = xt[i];
                float4 w = s_wih1[j * NF + i];     // ds_read_b128 broadcast
                ai = fmaf(w.x, xi, ai);
                af = fmaf(w.y, xi, af);
                ag = fmaf(w.z, xi, ag);
                ao = fmaf(w.w, xi, ao);
            }
            if (t > 0) {  // h1 == 0 at t==0: recurrent part contributes exactly 0
                #pragma unroll
                for (int k = 0; k < H1; ++k) {
                    const float hk = h1[k];
                    float4 w = s_whh1[j * H1 + k];
                    ai = fmaf(w.x, hk, ai);
                    af = fmaf(w.y, hk, af);
                    ag = fmaf(w.z, hk, ag);
                    ao = fmaf(w.w, hk, ao);
                }
            }
            const float ig = fast_sigmoid(ai);
            const float fg = fast_sigmoid(af);
            const float gg = fast_tanh(ag);
            const float og = fast_sigmoid(ao);
            const float c  = fmaf(fg, c1[j], ig * gg);  // c1==0 at t==0: exact
            c1[j]  = c;
            h1n[j] = og * fast_tanh(c);
            __builtin_amdgcn_sched_barrier(0);  // bound scheduler hoisting
        }
        #pragma unroll
        for (int j = 0; j < H1; ++j) h1[j] = h1n[j];

        // ---- layer 2 (consumes h1 of this timestep) ----
        float h2n[H2];
        #pragma unroll
        for (int j = 0; j < H2; ++j) {
            float4 bv = s_b2[j];
            float ai = bv.x, af = bv.y, ag = bv.z, ao = bv.w;
            #pragma unroll
            for (int k = 0; k < H1; ++k) {
                const float hk = h1[k];
                float4 w = s_wih2[j * H1 + k];
                ai = fmaf(w.x, hk, ai);
                af = fmaf(w.y, hk, af);
                ag = fmaf(w.z, hk, ag);
                ao = fmaf(w.w, hk, ao);
            }
            if (t > 0) {
                #pragma unroll
                for (int k = 0; k < H2; ++k) {
                    const float hk = h2v[k];
                    float4 w = s_whh2[j * H2 + k];
                    ai = fmaf(w.x, hk, ai);
                    af = fmaf(w.y, hk, af);
                    ag = fmaf(w.z, hk, ag);
                    ao = fmaf(w.w, hk, ao);
                }
            }
            const float ig = fast_sigmoid(ai);
            const float fg = fast_sigmoid(af);
            const float gg = fast_tanh(ag);
            const float og = fast_sigmoid(ao);
            const float c  = fmaf(fg, c2[j], ig * gg);
            c2[j]  = c;
            h2n[j] = og * fast_tanh(c);
            __builtin_amdgcn_sched_barrier(0);
        }
        #pragma unroll
        for (int j = 0; j < H2; ++j) h2v[j] = h2n[j];
    }

    // ---- write final h2: 32 contiguous bytes per thread, coalesced ----
    float4* op = reinterpret_cast<float4*>(out + (size_t)b * H2);
    op[0] = make_float4(h2v[0], h2v[1], h2v[2], h2v[3]);
    op[1] = make_float4(h2v[4], h2v[5], h2v[6], h2v[7]);
}

extern "C" void kernel_launch(void* const* d_in, const int* in_sizes, int n_in,
                              void* d_out, int out_size, void* d_ws, size_t ws_size,
                              hipStream_t stream)
{
    const float* x     = (const float*)d_in[0];
    const float* w_ih1 = (const float*)d_in[1];
    const float* w_hh1 = (const float*)d_in[2];
    const float* b_ih1 = (const float*)d_in[3];
    const float* b_hh1 = (const float*)d_in[4];
    const float* w_ih2 = (const float*)d_in[5];
    const float* w_hh2 = (const float*)d_in[6];
    const float* b_ih2 = (const float*)d_in[7];
    const float* b_hh2 = (const float*)d_in[8];
    float* out = (float*)d_out;

    const int batch = in_sizes[0] / (T * NF);
    const int block = 256;
    const int grid  = (batch + block - 1) / block;
    lstm2_fused<<<grid, block, 0, stream>>>(x, w_ih1, w_hh1, b_ih1, b_hh1,
                                            w_ih2, w_hh2, b_ih2, b_hh2,
                                            out, batch);
}